// Round 12
// baseline (484.649 us; speedup 1.0000x reference)
//
#include <hip/hip_runtime.h>
#include <hip/hip_cooperative_groups.h>
#include <hip/hip_bf16.h>
#include <math.h>

namespace cg = cooperative_groups;

typedef __hip_bfloat16 bf16;
typedef __attribute__((ext_vector_type(8))) short short8;
typedef __attribute__((ext_vector_type(4))) short short4v;
typedef __attribute__((ext_vector_type(4))) float f32x4;

#define NRES 2048
#define CDIM 256
#define PADK 48
#define POS 1440   // fused projection row stride (bf16)

static __device__ __forceinline__ float b2f(bf16 x) { return __bfloat162float(x); }
static __device__ __forceinline__ float us2f(short u) {
    return __uint_as_float(((unsigned)(unsigned short)u) << 16);
}
static __device__ __forceinline__ short f2s(float f) {
    bf16 h = __float2bfloat16(f);
    return *reinterpret_cast<short*>(&h);
}
static __device__ __forceinline__ bool flag_f32(const void* smask) {
    return *(const unsigned int*)smask == 0x3F800000u;
}
static __device__ __forceinline__ float dual_load(const void* p, size_t i, bool f32) {
    float vf = ((const float*)p)[f32 ? i : 0];
    float vb = b2f(((const bf16*)p)[f32 ? (size_t)0 : i]);
    return f32 ? vf : vb;
}

struct FusedArgs {
    const void* wsrc[8];
    bf16* wdst[8];
    int srcN[8];
    int nOff[8];
    int dstStride[8];
    float scl[8];
    int tileOff[9];
    const void* s;
    const void* cond;
    const void* z;
    const void* trans;
    const void* rots;
    const void* smask;
    const void* hweights;
    const void* Wb;
    const void* Wdz;
    const void* g_z;
    const void* b_z;
    const void* bg;
    const void* bbeta;
    bf16* condb;
    bf16* SQb;
    bf16* POb;
    bf16* Bzb;
    bf16* PZb;
    bf16* CATb;
    bf16* PWt;
    bf16* GWt;
    bf16* FWt;
    float* RT;
    float* RS;
    void* out;
};

// Phases (grid-stride task loops, all deps respected by grid.sync between phases):
//  P1: weight transpose (664) | cond cast (256) | LN(s) stats (256)          -> 1176 block-tasks
//  P2: gate/beta GEMM + modulate -> SQb                                      -> 512 block-tasks
//  P3: PO GEMM 2x2 (720) | z LN+proj (1024) | RT pack (96)                   -> 1840 block-tasks
//  P4: fused attention (q-split)                                             -> 1024 block-tasks
//  P5: final GEMM -> out                                                     -> 512 block-tasks
// LDS: buf[39232] (phase-aliased) + attn arrays (1152 B) = 40384 B -> 4 blocks/CU.
__global__ __launch_bounds__(256, 4) void k_fused(FusedArgs a) {
    cg::grid_group gridg = cg::this_grid();
    __shared__ char buf[39232];
    __shared__ float rowq[16], rowk[128], mk[128], mqv[16];

    const bool f32 = flag_f32(a.smask);
    const int t = threadIdx.x;
    const int wid = t >> 6, lane = t & 63, idx = lane & 15, quad = lane >> 4;
    const int G = gridDim.x;
    const short8 zero8 = {0,0,0,0,0,0,0,0};

    // ================= Phase 1 =================
    for (int b = blockIdx.x; b < 1176; b += G) {
        if (b < 664) {
            float* tile = (float*)buf;   // [32][33]
            int s_ = 0;
            while (b >= a.tileOff[s_ + 1]) ++s_;
            int rel = b - a.tileOff[s_];
            int ntT = a.srcN[s_] >> 5;
            int kt = rel / ntT, nt = rel % ntT;
            const void* src = a.wsrc[s_];
            int srcN = a.srcN[s_];
            float scl = a.scl[s_];
            int tx = t & 31, ty = t >> 5;
#pragma unroll
            for (int r = 0; r < 4; ++r)
                tile[(ty + r * 8) * 33 + tx] =
                    dual_load(src, (size_t)(kt * 32 + ty + r * 8) * srcN + nt * 32 + tx, f32);
            __syncthreads();
            bf16* dst = a.wdst[s_];
#pragma unroll
            for (int r = 0; r < 4; ++r)
                dst[(size_t)(nt * 32 + ty + r * 8 + a.nOff[s_]) * a.dstStride[s_] + kt * 32 + tx] =
                    __float2bfloat16(tile[tx * 33 + ty + r * 8] * scl);
        } else if (b < 920) {
            int i0 = (b - 664) * 2048;
            for (int i = t; i < 2048; i += 256)
                a.condb[i0 + i] = __float2bfloat16(dual_load(a.cond, (size_t)(i0 + i), f32));
        } else {
            int r0 = (b - 920) * 8;
            for (int rr = 0; rr < 2; ++rr) {
                int row = r0 + wid * 2 + rr;
                float sum = 0.f, sq = 0.f;
                for (int j = lane; j < CDIM; j += 64) {
                    float v = dual_load(a.s, (size_t)row * CDIM + j, f32);
                    sum += v; sq += v * v;
                }
                for (int off = 32; off; off >>= 1) { sum += __shfl_xor(sum, off); sq += __shfl_xor(sq, off); }
                if (lane == 0) {
                    float m = sum / CDIM;
                    float var = fmaxf(sq / CDIM - m * m, 0.f);
                    a.RS[row * 2 + 0] = m;
                    a.RS[row * 2 + 1] = rsqrtf(var + 1e-5f);
                }
            }
        }
        __syncthreads();
    }
    gridg.sync();

    // ================= Phase 2: gate/beta GEMM + modulate -> SQb =================
    for (int bb = blockIdx.x; bb < 512; bb += G) {
        int tid = bb * 4 + wid;
        int mt = tid >> 4, nt = tid & 15;
        const bf16* Ap = a.condb + (size_t)(mt * 16 + idx) * 256 + quad * 8;
        const bf16* B0 = a.GWt + (size_t)(nt * 16 + idx) * 256 + quad * 8;
        const bf16* B1 = a.GWt + (size_t)(256 + nt * 16 + idx) * 256 + quad * 8;
        f32x4 a0 = {0,0,0,0}, a1 = {0,0,0,0};
#pragma unroll
        for (int k = 0; k < 256; k += 32) {
            short8 af = *(const short8*)(Ap + k);
            a0 = __builtin_amdgcn_mfma_f32_16x16x32_bf16(af, *(const short8*)(B0 + k), a0, 0, 0, 0);
            a1 = __builtin_amdgcn_mfma_f32_16x16x32_bf16(af, *(const short8*)(B1 + k), a1, 0, 0, 0);
        }
        int ocol = nt * 16 + idx;
        float bgc = dual_load(a.bg, ocol, f32), bbc = dual_load(a.bbeta, ocol, f32);
        int orow = mt * 16 + quad * 4;
#pragma unroll
        for (int r = 0; r < 4; ++r) {
            int row = orow + r;
            float sv = dual_load(a.s, (size_t)row * 256 + ocol, f32);
            float xn = (sv - a.RS[row * 2]) * a.RS[row * 2 + 1];
            a.SQb[(size_t)row * 256 + ocol] = __float2bfloat16(xn * (a0[r] + bgc) + (a1[r] + bbc));
        }
    }
    gridg.sync();

    // ================= Phase 3: PO GEMM | z LN+proj | RT pack =================
    for (int b = blockIdx.x; b < 1840; b += G) {
        if (b < 720) {
            int tid = b * 4 + wid;                 // < 2880
            int mt = tid / 45, nt = tid % 45;      // N=1440 -> 45 col-tiles
            const bf16* Ap0 = a.SQb + (size_t)(mt * 32 + idx) * 256 + quad * 8;
            const bf16* Ap1 = Ap0 + (size_t)16 * 256;
            const bf16* Bp0 = a.PWt + (size_t)(nt * 32 + idx) * 256 + quad * 8;
            const bf16* Bp1 = Bp0 + (size_t)16 * 256;
            f32x4 a00 = {0,0,0,0}, a01 = {0,0,0,0}, a10 = {0,0,0,0}, a11 = {0,0,0,0};
#pragma unroll 4
            for (int k = 0; k < 256; k += 32) {
                short8 af0 = *(const short8*)(Ap0 + k);
                short8 af1 = *(const short8*)(Ap1 + k);
                short8 bf0 = *(const short8*)(Bp0 + k);
                short8 bf1 = *(const short8*)(Bp1 + k);
                a00 = __builtin_amdgcn_mfma_f32_16x16x32_bf16(af0, bf0, a00, 0, 0, 0);
                a01 = __builtin_amdgcn_mfma_f32_16x16x32_bf16(af0, bf1, a01, 0, 0, 0);
                a10 = __builtin_amdgcn_mfma_f32_16x16x32_bf16(af1, bf0, a10, 0, 0, 0);
                a11 = __builtin_amdgcn_mfma_f32_16x16x32_bf16(af1, bf1, a11, 0, 0, 0);
            }
            int orow = mt * 32 + quad * 4;
            int ocol = nt * 32 + idx;
#pragma unroll
            for (int r = 0; r < 4; ++r) {
                a.POb[(size_t)(orow + r) * POS + ocol] = __float2bfloat16(a00[r]);
                a.POb[(size_t)(orow + r) * POS + ocol + 16] = __float2bfloat16(a01[r]);
                a.POb[(size_t)(orow + r + 16) * POS + ocol] = __float2bfloat16(a10[r]);
                a.POb[(size_t)(orow + r + 16) * POS + ocol + 16] = __float2bfloat16(a11[r]);
            }
        } else if (b < 1744) {
            int zb = b - 720;
            float* wb  = (float*)buf;           // [32][8]
            float* wdz = (float*)(buf + 1024);  // [32][8]
            float* gz  = (float*)(buf + 2048);  // [32]
            float* bz  = (float*)(buf + 2176);  // [32]
            {
                int j = t >> 3, c = t & 7;
                wb[j * 8 + c] = 0.5773502691896258f * dual_load(a.Wb, t, f32);
                wdz[j * 8 + c] = dual_load(a.Wdz, t, f32);
            }
            if (t < 32) { gz[t] = dual_load(a.g_z, t, f32); bz[t] = dual_load(a.b_z, t, f32); }
            __syncthreads();
            size_t r = (size_t)zb * 256 + t;
            float zv[32];
            float sum = 0.f, sq = 0.f;
            if (f32) {
                const float4* zp = (const float4*)((const float*)a.z + r * 32);
#pragma unroll
                for (int j4 = 0; j4 < 8; ++j4) {
                    float4 v4 = zp[j4];
                    zv[j4 * 4 + 0] = v4.x; zv[j4 * 4 + 1] = v4.y; zv[j4 * 4 + 2] = v4.z; zv[j4 * 4 + 3] = v4.w;
                }
            } else {
                const bf16* zp = (const bf16*)a.z + r * 32;
#pragma unroll
                for (int j = 0; j < 32; ++j) zv[j] = b2f(zp[j]);
            }
#pragma unroll
            for (int j = 0; j < 32; ++j) { float v = zv[j]; sum += v; sq += v * v; }
            float m = sum / 32.f;
            float var = fmaxf(sq / 32.f - m * m, 0.f);
            float rstd = rsqrtf(var + 1e-5f);
#pragma unroll
            for (int j = 0; j < 32; ++j) zv[j] = (zv[j] - m) * rstd * gz[j] + bz[j];
            float bacc[8], pacc[8];
#pragma unroll
            for (int c = 0; c < 8; ++c) { bacc[c] = 0.f; pacc[c] = 0.f; }
            for (int j = 0; j < 32; ++j) {
                float v = zv[j];
#pragma unroll
                for (int c = 0; c < 8; ++c) { bacc[c] += v * wb[j * 8 + c]; pacc[c] += v * wdz[j * 8 + c]; }
            }
            int n = (int)(r >> 12);
            int q = (int)(r >> 7) & 31;
            int k = (int)r & 127;
#pragma unroll
            for (int h = 0; h < 8; ++h)
                a.Bzb[(size_t)n * 32768 + (size_t)h * 4096 + q * 128 + k] = __float2bfloat16(bacc[h]);
#pragma unroll
            for (int c = 0; c < 8; ++c)
                a.PZb[(((size_t)(n * 32 + q)) * 8 + c) * 128 + k] = __float2bfloat16(pacc[c]);
        } else {
            int i = (b - 1744) * 256 + t;
            int row = i / 12, c = i % 12;
            float v = (c < 9) ? dual_load(a.rots, (size_t)row * 9 + c, f32)
                              : dual_load(a.trans, (size_t)row * 3 + (c - 9), f32);
            a.RT[i] = v;
        }
        __syncthreads();
    }
    gridg.sync();

    // ================= Phase 4: fused attention (q-split) =================
    for (int ab = blockIdx.x; ab < 1024; ab += G) {
        short* VtS = (short*)buf;                  // [80][136]
        short* KpS = (short*)(buf + 21760);        // [128][32]
        short* QpS = (short*)(buf + 29952);        // [16][32]
        float* S   = (float*)(buf + 30976);        // [16][129]
        short* AsS = (short*)(buf + 30976);        // [16][136] overlays S
        float* OPT = (float*)(buf + 35328);        // [16][37]

        const int n = ab >> 4, h = (ab >> 1) & 7, qh = ab & 1;
        const int n32 = n * 32;
        const int q0 = qh * 16;
        const int rowg = n32 + q0;

        float hwv = dual_load(a.hweights, h, f32);
        float ptc = -0.5f * log1pf(expf(hwv)) * 0.09622504486493764f;  // * sqrt(1/108)
        float m2ptc = -2.f * ptc;

        // phase 0: register prefetches
        short8 afeat = *(const short8*)(a.POb + (size_t)(rowg + idx) * POS + h * 32 + quad * 8);
        short8 bfeat[2];
#pragma unroll
        for (int i = 0; i < 2; ++i) {
            int nt = wid * 2 + i;
            int kg = n32 + nt * 16 + idx - PADK;
            bfeat[i] = (kg >= 0 && kg < NRES)
                ? *(const short8*)(a.POb + (size_t)kg * POS + 256 + h * 32 + quad * 8) : zero8;
        }
        short bzr[8];
#pragma unroll
        for (int i = 0; i < 2; ++i) {
            int nt = wid * 2 + i;
            int k = nt * 16 + idx;
#pragma unroll
            for (int r = 0; r < 4; ++r) {
                int q = quad * 4 + r;
                bzr[i * 4 + r] = *(const short*)(a.Bzb + (size_t)n * 32768 + (size_t)h * 4096 + (q0 + q) * 128 + k);
            }
        }
        float4 kr0, kr1, kr2;
        float kmv = 0.f;
        short4v kpts[15];
        const int kgR = n32 + t - PADK;
        const bool validR = (t < 128) && (kgR >= 0 && kgR < NRES);
        if (validR) {
            const float4* rt = (const float4*)(a.RT + (size_t)kgR * 12);
            kr0 = rt[0]; kr1 = rt[1]; kr2 = rt[2];
            kmv = dual_load(a.smask, kgR, f32);
            const short4v* pp = (const short4v*)(a.POb + (size_t)kgR * POS + 960 + h * 60);
#pragma unroll
            for (int g = 0; g < 15; ++g) kpts[g] = pp[g];
        }
        float4 qr0, qr1, qr2;
        float qmv = 0.f;
        short8 qpts[3];
        if (t >= 240) {
            int q = t - 240;
            const float4* rt = (const float4*)(a.RT + (size_t)(rowg + q) * 12);
            qr0 = rt[0]; qr1 = rt[1]; qr2 = rt[2];
            qmv = dual_load(a.smask, rowg + q, f32);
            const short8* pp = (const short8*)(a.POb + (size_t)(rowg + q) * POS + 768 + h * 24);
#pragma unroll
            for (int g = 0; g < 3; ++g) qpts[g] = pp[g];
        }

        // phase 1: staging + rotation
        for (int i = t; i < 512; i += 256) {
            int k = i >> 2, g = i & 3;
            int kg = n32 + k - PADK;
            short8 v = zero8;
            if (kg >= 0 && kg < NRES)
                v = *(const short8*)(a.POb + (size_t)kg * POS + 512 + h * 32 + g * 8);
#pragma unroll
            for (int j = 0; j < 8; ++j) VtS[(g * 8 + j) * 136 + k] = v[j];
        }
        if (t < 128) {
            int k = t;
            if (validR) {
                const short* kp = (const short*)kpts;
                float s2 = 0.f;
#pragma unroll
                for (int j = 0; j < 20; ++j) {
                    float x = us2f(kp[j * 3 + 0]);
                    float y = us2f(kp[j * 3 + 1]);
                    float z = us2f(kp[j * 3 + 2]);
                    float p0 = kr0.x * x + kr0.y * y + kr0.z * z + kr2.y;
                    float p1 = kr0.w * x + kr1.x * y + kr1.y * z + kr2.z;
                    float p2 = kr1.z * x + kr1.w * y + kr2.x * z + kr2.w;
                    if (j < 8) {
                        KpS[k * 32 + j * 3 + 0] = f2s(p0);
                        KpS[k * 32 + j * 3 + 1] = f2s(p1);
                        KpS[k * 32 + j * 3 + 2] = f2s(p2);
                        s2 += p0 * p0 + p1 * p1 + p2 * p2;
                    } else {
                        int v = j - 8;
                        VtS[(32 + v * 3 + 0) * 136 + k] = f2s(p0);
                        VtS[(32 + v * 3 + 1) * 136 + k] = f2s(p1);
                        VtS[(32 + v * 3 + 2) * 136 + k] = f2s(p2);
                    }
                }
                *(short8*)(KpS + k * 32 + 24) = zero8;
                rowk[k] = ptc * s2;
                mk[k] = kmv;
            } else {
#pragma unroll
                for (int g = 0; g < 4; ++g) *(short8*)(KpS + k * 32 + g * 8) = zero8;
                for (int x = 32; x < 68; ++x) VtS[x * 136 + k] = 0;
                rowk[k] = 0.f; mk[k] = 0.f;
            }
        } else if (t >= 240) {
            int q = t - 240;
            const short* qp = (const short*)qpts;
            float s2 = 0.f;
#pragma unroll
            for (int p = 0; p < 8; ++p) {
                float x = us2f(qp[p * 3 + 0]);
                float y = us2f(qp[p * 3 + 1]);
                float z = us2f(qp[p * 3 + 2]);
                float p0 = qr0.x * x + qr0.y * y + qr0.z * z + qr2.y;
                float p1 = qr0.w * x + qr1.x * y + qr1.y * z + qr2.z;
                float p2 = qr1.z * x + qr1.w * y + qr2.x * z + qr2.w;
                QpS[q * 32 + p * 3 + 0] = f2s(m2ptc * p0);
                QpS[q * 32 + p * 3 + 1] = f2s(m2ptc * p1);
                QpS[q * 32 + p * 3 + 2] = f2s(m2ptc * p2);
                s2 += p0 * p0 + p1 * p1 + p2 * p2;
            }
            *(short8*)(QpS + q * 32 + 24) = zero8;
            rowq[q] = ptc * s2;
            mqv[q] = qmv;
        }
        __syncthreads();

        // phase 2: QK -> S
        short8 a2 = *(const short8*)(QpS + idx * 32 + quad * 8);
#pragma unroll
        for (int i = 0; i < 2; ++i) {
            int nt = wid * 2 + i;
            f32x4 acc = {0.f, 0.f, 0.f, 0.f};
            acc = __builtin_amdgcn_mfma_f32_16x16x32_bf16(afeat, bfeat[i], acc, 0, 0, 0);
            short8 b2 = *(const short8*)(KpS + (nt * 16 + idx) * 32 + quad * 8);
            acc = __builtin_amdgcn_mfma_f32_16x16x32_bf16(a2, b2, acc, 0, 0, 0);
            int k = nt * 16 + idx;
#pragma unroll
            for (int r = 0; r < 4; ++r) {
                int q = quad * 4 + r;
                float msk = 1e8f * (mqv[q] * mk[k] - 1.f);
                S[q * 129 + k] = acc[r] + us2f(bzr[i * 4 + r]) + rowq[q] + rowk[k] + msk;
            }
        }
        __syncthreads();

        // phase 3: softmax
        float sa0[4], sa1[4];
#pragma unroll
        for (int rr = 0; rr < 4; ++rr) {
            int q = wid * 4 + rr;
            float v0 = S[q * 129 + lane], v1 = S[q * 129 + lane + 64];
            float mx = fmaxf(v0, v1);
            for (int off = 32; off; off >>= 1) mx = fmaxf(mx, __shfl_xor(mx, off));
            float e0 = expf(v0 - mx), e1 = expf(v1 - mx);
            float sm = e0 + e1;
            for (int off = 32; off; off >>= 1) sm += __shfl_xor(sm, off);
            float inv = 1.f / sm;
            sa0[rr] = e0 * inv; sa1[rr] = e1 * inv;
        }
        __syncthreads();
#pragma unroll
        for (int rr = 0; rr < 4; ++rr) {
            int q = wid * 4 + rr;
            AsS[q * 136 + lane] = f2s(sa0[rr]);
            AsS[q * 136 + lane + 64] = f2s(sa1[rr]);
        }
        __syncthreads();

        // phase 4: PV MFMA + o_pair
        short8 pz0[8];
        if (t < 128) {
            int q = t >> 3, c = t & 7;
            const short8* pzp = (const short8*)(a.PZb + ((size_t)(rowg + q) * 8 + c) * 128);
#pragma unroll
            for (int k8 = 0; k8 < 8; ++k8) pz0[k8] = pzp[k8];
        }
#pragma unroll
        for (int i = 0; i < 2; ++i) {
            int tt = wid + i * 4;
            if (tt >= 5) break;
            int nt = tt;
            f32x4 acc = {0.f, 0.f, 0.f, 0.f};
#pragma unroll
            for (int kk = 0; kk < 4; ++kk) {
                short8 af  = *(const short8*)(AsS + idx * 136 + kk * 32 + quad * 8);
                short8 bfv = *(const short8*)(VtS + (nt * 16 + idx) * 136 + kk * 32 + quad * 8);
                acc = __builtin_amdgcn_mfma_f32_16x16x32_bf16(af, bfv, acc, 0, 0, 0);
            }
            int x = nt * 16 + idx;
#pragma unroll
            for (int r = 0; r < 4; ++r) {
                int q = quad * 4 + r;
                if (x < 32)
                    a.CATb[(size_t)(rowg + q) * 704 + h * 32 + x] = __float2bfloat16(acc[r]);
                else if (x < 68)
                    OPT[q * 37 + (x - 32)] = acc[r];
            }
        }
        if (t < 128) {
            int q = t >> 3, c = t & 7;
            const short8* pzp = (const short8*)(a.PZb + ((size_t)(rowg + q) * 8 + c) * 128);
            const short8* asp = (const short8*)(AsS + q * 136);
            float acc = 0.f;
#pragma unroll
            for (int k8 = 0; k8 < 8; ++k8) {
                short8 pv = pz0[k8];
                short8 av = asp[k8];
#pragma unroll
                for (int j = 0; j < 8; ++j) acc += us2f(av[j]) * us2f(pv[j]);
            }
#pragma unroll
            for (int k8 = 0; k8 < 8; ++k8) pz0[k8] = pzp[8 + k8];
#pragma unroll
            for (int k8 = 0; k8 < 8; ++k8) {
                short8 pv = pz0[k8];
                short8 av = asp[8 + k8];
#pragma unroll
                for (int j = 0; j < 8; ++j) acc += us2f(av[j]) * us2f(pv[j]);
            }
            a.CATb[(size_t)(rowg + q) * 704 + 640 + h * 8 + c] = __float2bfloat16(acc);
        }
        __syncthreads();

        // phase 5: inverse rotation + norms
        if (t < 192) {
            int q = t / 12, v = t % 12;
            int g = rowg + q;
            const float4* rt = (const float4*)(a.RT + (size_t)g * 12);
            float4 r0 = rt[0], r1 = rt[1], r2 = rt[2];
            float x = OPT[q * 37 + v * 3 + 0] - r2.y;
            float y = OPT[q * 37 + v * 3 + 1] - r2.z;
            float z = OPT[q * 37 + v * 3 + 2] - r2.w;
            float o0 = r0.x * x + r0.w * y + r1.z * z;   // R^T (x - t)
            float o1 = r0.y * x + r1.x * y + r1.w * z;
            float o2 = r0.z * x + r1.y * y + r2.x * z;
            size_t cb = (size_t)g * 704;
            a.CATb[cb + 256 + (h * 12 + v) * 3 + 0] = __float2bfloat16(o0);
            a.CATb[cb + 256 + (h * 12 + v) * 3 + 1] = __float2bfloat16(o1);
            a.CATb[cb + 256 + (h * 12 + v) * 3 + 2] = __float2bfloat16(o2);
            a.CATb[cb + 544 + h * 12 + v] = __float2bfloat16(sqrtf(o0 * o0 + o1 * o1 + o2 * o2 + 1e-8f));
        }
        __syncthreads();
    }
    gridg.sync();

    // ================= Phase 5: final GEMM out = CATb @ FWt^T =================
    for (int bb = blockIdx.x; bb < 512; bb += G) {
        int tid = bb * 4 + wid;
        int mt = tid >> 4, nt = tid & 15;
        const bf16* Ap = a.CATb + (size_t)(mt * 16 + idx) * 704 + quad * 8;
        const bf16* Bp = a.FWt + (size_t)(nt * 16 + idx) * 704 + quad * 8;
        f32x4 acc = {0.f, 0.f, 0.f, 0.f};
#pragma unroll 4
        for (int k = 0; k < 704; k += 32) {
            short8 af = *(const short8*)(Ap + k);
            short8 bfv = *(const short8*)(Bp + k);
            acc = __builtin_amdgcn_mfma_f32_16x16x32_bf16(af, bfv, acc, 0, 0, 0);
        }
        int orow = mt * 16 + quad * 4;
        int ocol = nt * 16 + idx;
        if (f32) {
            float* C = (float*)a.out;
#pragma unroll
            for (int r = 0; r < 4; ++r) C[(size_t)(orow + r) * 256 + ocol] = acc[r];
        } else {
            bf16* C = (bf16*)a.out;
#pragma unroll
            for (int r = 0; r < 4; ++r) C[(size_t)(orow + r) * 256 + ocol] = __float2bfloat16(acc[r]);
        }
    }
}

extern "C" void kernel_launch(void* const* d_in, const int* in_sizes, int n_in,
                              void* d_out, int out_size, void* d_ws, size_t ws_size,
                              hipStream_t stream) {
    const void* s       = d_in[0];
    const void* cond    = d_in[1];
    const void* z       = d_in[2];
    const void* trans   = d_in[3];
    const void* rots    = d_in[4];
    const void* s_mask  = d_in[5];
    const void* Wq      = d_in[6];
    const void* Wk      = d_in[7];
    const void* Wv      = d_in[8];
    const void* Wqp     = d_in[9];
    const void* Wkvp    = d_in[10];
    const void* Wb      = d_in[11];
    const void* Wdz     = d_in[12];
    const void* hweights= d_in[13];
    const void* Wout    = d_in[14];
    const void* Wg      = d_in[15];
    const void* bg      = d_in[16];
    const void* Wbeta   = d_in[17];
    const void* bbeta   = d_in[18];
    const void* g_z     = d_in[19];
    const void* b_z     = d_in[20];

    float* ws = (float*)d_ws;
    FusedArgs a;
    a.POb   = (bf16*)(ws);             // [2048][1440]
    a.Bzb   = (bf16*)(ws + 1474560);   // [64][8][32][128]
    a.PZb   = (bf16*)(ws + 2523136);   // [2048][8][128]
    a.SQb   = (bf16*)(ws + 3571712);   // [2048][256]
    a.condb = (bf16*)(ws + 3833856);   // [2048][256]
    a.CATb  = (bf16*)(ws + 4358144);   // [2048][704]
    a.PWt   = (bf16*)(ws + 5079040);   // [1440][256]
    a.GWt   = (bf16*)(ws + 5263360);   // [512][256]
    a.FWt   = (bf16*)(ws + 5328896);   // [256][704]
    a.RT    = (float*)(ws + 5419008);  // [2048][12] f32
    a.RS    = (float*)(ws + 5443584);  // [2048][2] f32

    const float qkscale = 0.10206207261596575f;  // sqrt(1/96), folded into Wq
    a.wsrc[0] = Wq;   a.wdst[0] = a.PWt; a.srcN[0] = 256; a.nOff[0] = 0;   a.dstStride[0] = 256; a.scl[0] = qkscale;
    a.wsrc[1] = Wk;   a.wdst[1] = a.PWt; a.srcN[1] = 256; a.nOff[1] = 256; a.dstStride[1] = 256; a.scl[1] = 1.f;
    a.wsrc[2] = Wv;   a.wdst[2] = a.PWt; a.srcN[2] = 256; a.nOff[2] = 512; a.dstStride[2] = 256; a.scl[2] = 1.f;
    a.wsrc[3] = Wqp;  a.wdst[3] = a.PWt; a.srcN[3] = 192; a.nOff[3] = 768; a.dstStride[3] = 256; a.scl[3] = 1.f;
    a.wsrc[4] = Wkvp; a.wdst[4] = a.PWt; a.srcN[4] = 480; a.nOff[4] = 960; a.dstStride[4] = 256; a.scl[4] = 1.f;
    a.wsrc[5] = Wg;   a.wdst[5] = a.GWt; a.srcN[5] = 256; a.nOff[5] = 0;   a.dstStride[5] = 256; a.scl[5] = 1.f;
    a.wsrc[6] = Wbeta;a.wdst[6] = a.GWt; a.srcN[6] = 256; a.nOff[6] = 256; a.dstStride[6] = 256; a.scl[6] = 1.f;
    a.wsrc[7] = Wout; a.wdst[7] = a.FWt; a.srcN[7] = 256; a.nOff[7] = 0;   a.dstStride[7] = 704; a.scl[7] = 1.f;
    int tc[8] = {64, 64, 64, 48, 120, 64, 64, 176};
    a.tileOff[0] = 0;
    for (int i = 0; i < 8; ++i) a.tileOff[i + 1] = a.tileOff[i] + tc[i];
    a.s = s; a.cond = cond; a.z = z; a.trans = trans; a.rots = rots;
    a.smask = s_mask; a.hweights = hweights;
    a.Wb = Wb; a.Wdz = Wdz; a.g_z = g_z; a.b_z = b_z;
    a.bg = bg; a.bbeta = bbeta;
    a.out = d_out;

    // co-resident grid (deterministic query; grid-stride loops are size-agnostic)
    int bpc = 0;
    if (hipOccupancyMaxActiveBlocksPerMultiprocessor(&bpc, (const void*)k_fused, 256, 0) != hipSuccess || bpc < 1)
        bpc = 2;
    if (bpc > 4) bpc = 4;
    int grid = bpc * 256;
    if (grid > 1024) grid = 1024;

    void* args[] = { (void*)&a };
    hipLaunchCooperativeKernel((const void*)k_fused, dim3(grid), dim3(256), args, 0, stream);
}

// Round 13
// 167.836 us; speedup vs baseline: 2.8876x; 2.8876x over previous
//
#include <hip/hip_runtime.h>
#include <hip/hip_bf16.h>
#include <math.h>

typedef __hip_bfloat16 bf16;
typedef __attribute__((ext_vector_type(8))) short short8;
typedef __attribute__((ext_vector_type(4))) short short4v;
typedef __attribute__((ext_vector_type(4))) float f32x4;

#define NRES 2048
#define CDIM 256
#define PADK 48
#define POS 1440   // fused projection row stride (bf16)

static __device__ __forceinline__ float b2f(bf16 x) { return __bfloat162float(x); }
static __device__ __forceinline__ float us2f(short u) {
    return __uint_as_float(((unsigned)(unsigned short)u) << 16);
}
static __device__ __forceinline__ short f2s(float f) {
    bf16 h = __float2bfloat16(f);
    return *reinterpret_cast<short*>(&h);
}
static __device__ __forceinline__ bool flag_f32(const void* smask) {
    return *(const unsigned int*)smask == 0x3F800000u;
}
static __device__ __forceinline__ float dual_load(const void* p, size_t i, bool f32) {
    float vf = ((const float*)p)[f32 ? i : 0];
    float vb = b2f(((const bf16*)p)[f32 ? (size_t)0 : i]);
    return f32 ? vf : vb;
}

// ---------------- Kernel 1: prep = weight transpose | cond cast | LN(s) stats ----------------
struct PrepTable {
    const void* src[8];
    bf16* dst[8];
    int srcN[8];
    int nOff[8];
    int dstStride[8];
    float scl[8];
    int tileOff[9];
    const void* s;
    float* RS;          // [2048][2] = {mean, rstd}
    const void* cond;
    bf16* condb;
};
__global__ __launch_bounds__(256) void k_prep(PrepTable tb, const void* __restrict__ smask) {
    __shared__ float tile[32][33];
    bool f32 = flag_f32(smask);
    int b = blockIdx.x;
    int t = threadIdx.x;
    if (b < tb.tileOff[8]) {
        // --- weight transpose segment ---
        int s = 0;
        while (b >= tb.tileOff[s + 1]) ++s;
        int rel = b - tb.tileOff[s];
        int ntTiles = tb.srcN[s] >> 5;
        int kt = rel / ntTiles, nt = rel % ntTiles;
        const void* src = tb.src[s];
        int srcN = tb.srcN[s];
        float scl = tb.scl[s];
        int tx = t & 31, ty = t >> 5;
#pragma unroll
        for (int r = 0; r < 4; ++r) {
            int srow = kt * 32 + ty + r * 8;
            int scol = nt * 32 + tx;
            tile[ty + r * 8][tx] = dual_load(src, (size_t)srow * srcN + scol, f32);
        }
        __syncthreads();
        bf16* dst = tb.dst[s];
#pragma unroll
        for (int r = 0; r < 4; ++r) {
            int n = nt * 32 + ty + r * 8 + tb.nOff[s];
            int k = kt * 32 + tx;
            dst[(size_t)n * tb.dstStride[s] + k] = __float2bfloat16(tile[tx][ty + r * 8] * scl);
        }
        return;
    }
    b -= tb.tileOff[8];
    if (b < 256) {
        // --- cond cast segment ---
        int i0 = b * 2048;
        for (int i = t; i < 2048; i += 256)
            tb.condb[i0 + i] = __float2bfloat16(dual_load(tb.cond, (size_t)(i0 + i), f32));
        return;
    }
    b -= 256;
    // --- LN(s) stats segment: 8 rows/block, 2 rows/wave, no LDS ---
    {
        int wave = t >> 6, lane = t & 63;
        int r0 = b * 8;
        for (int rr = 0; rr < 2; ++rr) {
            int row = r0 + wave * 2 + rr;
            float sum = 0.f, sq = 0.f;
            for (int j = lane; j < CDIM; j += 64) {
                float v = dual_load(tb.s, (size_t)row * CDIM + j, f32);
                sum += v; sq += v * v;
            }
            for (int off = 32; off; off >>= 1) { sum += __shfl_xor(sum, off); sq += __shfl_xor(sq, off); }
            if (lane == 0) {
                float m = sum / CDIM;
                float var = fmaxf(sq / CDIM - m * m, 0.f);
                tb.RS[row * 2 + 0] = m;
                tb.RS[row * 2 + 1] = rsqrtf(var + 1e-5f);
            }
        }
    }
}

// ---------------- Kernel 2: gate/beta GEMM (bf16 condb A) + modulate epilogue (inline LN) -> SQb ----------------
__global__ __launch_bounds__(256) void k_gb(
    const bf16* __restrict__ condb, const bf16* __restrict__ GWt,
    const void* __restrict__ s, const float* __restrict__ RS,
    const void* __restrict__ bg, const void* __restrict__ bbeta,
    const void* __restrict__ smask, bf16* __restrict__ SQb)
{
    bool f32 = flag_f32(smask);
    int wid = threadIdx.x >> 6, lane = threadIdx.x & 63;
    int tid = blockIdx.x * 4 + wid;
    int mt = tid >> 4, nt = tid & 15;
    int idx = lane & 15, quad = lane >> 4;
    const bf16* Ap = condb + (size_t)(mt * 16 + idx) * 256 + quad * 8;
    const bf16* B0 = GWt + (size_t)(nt * 16 + idx) * 256 + quad * 8;
    const bf16* B1 = GWt + (size_t)(256 + nt * 16 + idx) * 256 + quad * 8;
    f32x4 a0 = {0,0,0,0}, a1 = {0,0,0,0};
#pragma unroll
    for (int k = 0; k < 256; k += 32) {
        short8 af = *(const short8*)(Ap + k);
        a0 = __builtin_amdgcn_mfma_f32_16x16x32_bf16(af, *(const short8*)(B0 + k), a0, 0, 0, 0);
        a1 = __builtin_amdgcn_mfma_f32_16x16x32_bf16(af, *(const short8*)(B1 + k), a1, 0, 0, 0);
    }
    int ocol = nt * 16 + idx;
    float bgc = dual_load(bg, ocol, f32), bbc = dual_load(bbeta, ocol, f32);
    int orow = mt * 16 + quad * 4;
#pragma unroll
    for (int r = 0; r < 4; ++r) {
        int row = orow + r;
        float sv = dual_load(s, (size_t)row * 256 + ocol, f32);
        float xn = (sv - RS[row * 2]) * RS[row * 2 + 1];
        SQb[(size_t)row * 256 + ocol] = __float2bfloat16(xn * (a0[r] + bgc) + (a1[r] + bbc));
    }
}

// ---------------- Kernel 3: PO GEMM (720) | z LN+proj (1024) | RT pack (96) ----------------
struct GzArgs {
    const bf16* SQb;
    const bf16* PWt;
    bf16* POb;
    const void* z;
    const void* Wb;
    const void* Wdz;
    const void* g_z;
    const void* b_z;
    bf16* Bzb;
    bf16* PZb;
    const void* rots;
    const void* trans;
    float* RT;
};
__global__ __launch_bounds__(256) void k_gemm_z(GzArgs a, const void* __restrict__ smask) {
    __shared__ float wb[32][8], wdz[32][8], gz[32], bz[32];
    bool f32 = flag_f32(smask);
    int b = blockIdx.x;
    int t = threadIdx.x;
    int wid = t >> 6, lane = t & 63;
    int idx = lane & 15, quad = lane >> 4;
    if (b < 720) {
        // --- PO GEMM 2x2 macro-tile ---
        int tid = b * 4 + wid;                 // < 2880
        int mt = tid / 45, nt = tid % 45;
        const bf16* Ap0 = a.SQb + (size_t)(mt * 32 + idx) * 256 + quad * 8;
        const bf16* Ap1 = Ap0 + (size_t)16 * 256;
        const bf16* Bp0 = a.PWt + (size_t)(nt * 32 + idx) * 256 + quad * 8;
        const bf16* Bp1 = Bp0 + (size_t)16 * 256;
        f32x4 a00 = {0,0,0,0}, a01 = {0,0,0,0}, a10 = {0,0,0,0}, a11 = {0,0,0,0};
#pragma unroll 4
        for (int k = 0; k < 256; k += 32) {
            short8 af0 = *(const short8*)(Ap0 + k);
            short8 af1 = *(const short8*)(Ap1 + k);
            short8 bf0 = *(const short8*)(Bp0 + k);
            short8 bf1 = *(const short8*)(Bp1 + k);
            a00 = __builtin_amdgcn_mfma_f32_16x16x32_bf16(af0, bf0, a00, 0, 0, 0);
            a01 = __builtin_amdgcn_mfma_f32_16x16x32_bf16(af0, bf1, a01, 0, 0, 0);
            a10 = __builtin_amdgcn_mfma_f32_16x16x32_bf16(af1, bf0, a10, 0, 0, 0);
            a11 = __builtin_amdgcn_mfma_f32_16x16x32_bf16(af1, bf1, a11, 0, 0, 0);
        }
        int orow = mt * 32 + quad * 4;
        int ocol = nt * 32 + idx;
#pragma unroll
        for (int r = 0; r < 4; ++r) {
            a.POb[(size_t)(orow + r) * POS + ocol] = __float2bfloat16(a00[r]);
            a.POb[(size_t)(orow + r) * POS + ocol + 16] = __float2bfloat16(a01[r]);
            a.POb[(size_t)(orow + r + 16) * POS + ocol] = __float2bfloat16(a10[r]);
            a.POb[(size_t)(orow + r + 16) * POS + ocol + 16] = __float2bfloat16(a11[r]);
        }
        return;
    }
    b -= 720;
    if (b < 1024) {
        // --- z segment: LN + Bz (bscale folded) + PZ ---
        {
            int j = t >> 3, c = t & 7;
            wb[j][c] = 0.5773502691896258f * dual_load(a.Wb, t, f32);
            wdz[j][c] = dual_load(a.Wdz, t, f32);
        }
        if (t < 32) { gz[t] = dual_load(a.g_z, t, f32); bz[t] = dual_load(a.b_z, t, f32); }
        __syncthreads();
        size_t r = (size_t)b * 256 + t;
        float zv[32];
        float sum = 0.f, sq = 0.f;
        if (f32) {
            const float4* zp = (const float4*)((const float*)a.z + r * 32);
#pragma unroll
            for (int j4 = 0; j4 < 8; ++j4) {
                float4 v4 = zp[j4];
                zv[j4 * 4 + 0] = v4.x; zv[j4 * 4 + 1] = v4.y; zv[j4 * 4 + 2] = v4.z; zv[j4 * 4 + 3] = v4.w;
            }
        } else {
            const bf16* zp = (const bf16*)a.z + r * 32;
#pragma unroll
            for (int j = 0; j < 32; ++j) zv[j] = b2f(zp[j]);
        }
#pragma unroll
        for (int j = 0; j < 32; ++j) { float v = zv[j]; sum += v; sq += v * v; }
        float m = sum / 32.f;
        float var = fmaxf(sq / 32.f - m * m, 0.f);
        float rstd = rsqrtf(var + 1e-5f);
#pragma unroll
        for (int j = 0; j < 32; ++j) zv[j] = (zv[j] - m) * rstd * gz[j] + bz[j];
        float bacc[8], pacc[8];
#pragma unroll
        for (int c = 0; c < 8; ++c) { bacc[c] = 0.f; pacc[c] = 0.f; }
        for (int j = 0; j < 32; ++j) {
            float v = zv[j];
#pragma unroll
            for (int c = 0; c < 8; ++c) { bacc[c] += v * wb[j][c]; pacc[c] += v * wdz[j][c]; }
        }
        int n = (int)(r >> 12);
        int q = (int)(r >> 7) & 31;
        int k = (int)r & 127;
#pragma unroll
        for (int h = 0; h < 8; ++h)
            a.Bzb[(size_t)n * 32768 + (size_t)h * 4096 + q * 128 + k] = __float2bfloat16(bacc[h]);
#pragma unroll
        for (int c = 0; c < 8; ++c)
            a.PZb[(((size_t)(n * 32 + q)) * 8 + c) * 128 + k] = __float2bfloat16(pacc[c]);
        return;
    }
    b -= 1024;
    // --- RT pack segment ---
    int i = b * 256 + t;
    int row = i / 12, c = i % 12;
    float v = (c < 9) ? dual_load(a.rots, (size_t)row * 9 + c, f32)
                      : dual_load(a.trans, (size_t)row * 3 + (c - 9), f32);
    a.RT[i] = v;
}

// ---------------- Kernel 4: fused attention, q-split, forced 4 blocks/CU ----------------
// LDS (bytes), total 39232 + small arrays; __launch_bounds__(256,4).
//   Vt  s16[80][136]  @0      (21760)
//   Kp  s16[128][32]  @21760  (8192)
//   Qp  s16[16][32]   @29952  (1024)
//   S   f32[16][129]  @30976  [phase 2-3a] | As s16[16][136] overlays [3b+] | OPT f32[16][37] @35328 [4+]
__global__ __launch_bounds__(256, 4) void k_attn_out(
    const bf16* __restrict__ POb,
    const bf16* __restrict__ Bzb, const bf16* __restrict__ PZb,
    const float* __restrict__ RT,
    const void* __restrict__ smask, const void* __restrict__ head_weights,
    bf16* __restrict__ CATb)
{
    __shared__ char buf[39232];
    __shared__ float rowq[16], rowk[128], mk[128], mqv[16];
    short* VtS = (short*)buf;                  // stride 136
    short* KpS = (short*)(buf + 21760);        // stride 32
    short* QpS = (short*)(buf + 29952);        // stride 32
    float* S   = (float*)(buf + 30976);        // stride 129
    short* AsS = (short*)(buf + 30976);        // stride 136
    float* OPT = (float*)(buf + 35328);        // stride 37

    const int bx = blockIdx.x;
    const int n = bx >> 4, h = (bx >> 1) & 7, qh = bx & 1;
    const int t = threadIdx.x;
    const bool f32 = flag_f32(smask);
    const int n32 = n * 32;
    const int q0 = qh * 16;
    const int rowg = n32 + q0;

    const int wid = t >> 6, lane = t & 63, idx = lane & 15, quad = lane >> 4;

    float hwv = dual_load(head_weights, h, f32);
    float ptc = -0.5f * log1pf(expf(hwv)) * 0.09622504486493764f;  // * sqrt(1/108)
    float m2ptc = -2.f * ptc;
    const short8 zero8 = {0,0,0,0,0,0,0,0};

    // ---- phase 0: register prefetches ----
    short8 afeat = *(const short8*)(POb + (size_t)(rowg + idx) * POS + h * 32 + quad * 8);
    short8 bfeat[2];
#pragma unroll
    for (int i = 0; i < 2; ++i) {
        int nt = wid * 2 + i;
        int kg = n32 + nt * 16 + idx - PADK;
        bfeat[i] = (kg >= 0 && kg < NRES)
            ? *(const short8*)(POb + (size_t)kg * POS + 256 + h * 32 + quad * 8) : zero8;
    }
    short bzr[8];
#pragma unroll
    for (int i = 0; i < 2; ++i) {
        int nt = wid * 2 + i;
        int k = nt * 16 + idx;
#pragma unroll
        for (int r = 0; r < 4; ++r) {
            int q = quad * 4 + r;
            bzr[i * 4 + r] = *(const short*)(Bzb + (size_t)n * 32768 + (size_t)h * 4096 + (q0 + q) * 128 + k);
        }
    }
    float4 kr0, kr1, kr2;
    float kmv = 0.f;
    short4v kpts[15];
    const int kgR = n32 + t - PADK;
    const bool validR = (t < 128) && (kgR >= 0 && kgR < NRES);
    if (validR) {
        const float4* rt = (const float4*)(RT + (size_t)kgR * 12);
        kr0 = rt[0]; kr1 = rt[1]; kr2 = rt[2];
        kmv = dual_load(smask, kgR, f32);
        const short4v* pp = (const short4v*)(POb + (size_t)kgR * POS + 960 + h * 60);
#pragma unroll
        for (int g = 0; g < 15; ++g) kpts[g] = pp[g];
    }
    float4 qr0, qr1, qr2;
    float qmv = 0.f;
    short8 qpts[3];
    if (t >= 240) {
        int q = t - 240;
        const float4* rt = (const float4*)(RT + (size_t)(rowg + q) * 12);
        qr0 = rt[0]; qr1 = rt[1]; qr2 = rt[2];
        qmv = dual_load(smask, rowg + q, f32);
        const short8* pp = (const short8*)(POb + (size_t)(rowg + q) * POS + 768 + h * 24);
#pragma unroll
        for (int g = 0; g < 3; ++g) qpts[g] = pp[g];
    }

    // ---- phase 1: staging + rotation ----
    for (int i = t; i < 512; i += 256) {  // Vt feature rows (transposed scatter)
        int k = i >> 2, g = i & 3;
        int kg = n32 + k - PADK;
        short8 v = zero8;
        if (kg >= 0 && kg < NRES)
            v = *(const short8*)(POb + (size_t)kg * POS + 512 + h * 32 + g * 8);
#pragma unroll
        for (int j = 0; j < 8; ++j) VtS[(g * 8 + j) * 136 + k] = v[j];
    }
    if (t < 128) {
        int k = t;
        if (validR) {
            const short* kp = (const short*)kpts;
            float s2 = 0.f;
#pragma unroll
            for (int j = 0; j < 20; ++j) {
                float x = us2f(kp[j * 3 + 0]);
                float y = us2f(kp[j * 3 + 1]);
                float z = us2f(kp[j * 3 + 2]);
                float p0 = kr0.x * x + kr0.y * y + kr0.z * z + kr2.y;
                float p1 = kr0.w * x + kr1.x * y + kr1.y * z + kr2.z;
                float p2 = kr1.z * x + kr1.w * y + kr2.x * z + kr2.w;
                if (j < 8) {
                    KpS[k * 32 + j * 3 + 0] = f2s(p0);
                    KpS[k * 32 + j * 3 + 1] = f2s(p1);
                    KpS[k * 32 + j * 3 + 2] = f2s(p2);
                    s2 += p0 * p0 + p1 * p1 + p2 * p2;
                } else {
                    int v = j - 8;
                    VtS[(32 + v * 3 + 0) * 136 + k] = f2s(p0);
                    VtS[(32 + v * 3 + 1) * 136 + k] = f2s(p1);
                    VtS[(32 + v * 3 + 2) * 136 + k] = f2s(p2);
                }
            }
            *(short8*)(KpS + k * 32 + 24) = zero8;
            rowk[k] = ptc * s2;
            mk[k] = kmv;
        } else {
#pragma unroll
            for (int g = 0; g < 4; ++g) *(short8*)(KpS + k * 32 + g * 8) = zero8;
            for (int x = 32; x < 68; ++x) VtS[x * 136 + k] = 0;
            rowk[k] = 0.f; mk[k] = 0.f;
        }
    } else if (t >= 240) {
        int q = t - 240;
        const short* qp = (const short*)qpts;
        float s2 = 0.f;
#pragma unroll
        for (int p = 0; p < 8; ++p) {
            float x = us2f(qp[p * 3 + 0]);
            float y = us2f(qp[p * 3 + 1]);
            float z = us2f(qp[p * 3 + 2]);
            float p0 = qr0.x * x + qr0.y * y + qr0.z * z + qr2.y;
            float p1 = qr0.w * x + qr1.x * y + qr1.y * z + qr2.z;
            float p2 = qr1.z * x + qr1.w * y + qr2.x * z + qr2.w;
            QpS[q * 32 + p * 3 + 0] = f2s(m2ptc * p0);
            QpS[q * 32 + p * 3 + 1] = f2s(m2ptc * p1);
            QpS[q * 32 + p * 3 + 2] = f2s(m2ptc * p2);
            s2 += p0 * p0 + p1 * p1 + p2 * p2;
        }
        *(short8*)(QpS + q * 32 + 24) = zero8;
        rowq[q] = ptc * s2;
        mqv[q] = qmv;
    }
    __syncthreads();

    // ---- phase 2: QK (features from regs + points from LDS) -> S ----
    short8 a2 = *(const short8*)(QpS + idx * 32 + quad * 8);
#pragma unroll
    for (int i = 0; i < 2; ++i) {
        int nt = wid * 2 + i;
        f32x4 acc = {0.f, 0.f, 0.f, 0.f};
        acc = __builtin_amdgcn_mfma_f32_16x16x32_bf16(afeat, bfeat[i], acc, 0, 0, 0);
        short8 b2 = *(const short8*)(KpS + (nt * 16 + idx) * 32 + quad * 8);
        acc = __builtin_amdgcn_mfma_f32_16x16x32_bf16(a2, b2, acc, 0, 0, 0);
        int k = nt * 16 + idx;
#pragma unroll
        for (int r = 0; r < 4; ++r) {
            int q = quad * 4 + r;
            float msk = 1e8f * (mqv[q] * mk[k] - 1.f);
            S[q * 129 + k] = acc[r] + us2f(bzr[i * 4 + r]) + rowq[q] + rowk[k] + msk;
        }
    }
    __syncthreads();

    // ---- phase 3: softmax (read->regs, barrier, write As over S) ----
    float sa0[4], sa1[4];
#pragma unroll
    for (int rr = 0; rr < 4; ++rr) {
        int q = wid * 4 + rr;
        float v0 = S[q * 129 + lane], v1 = S[q * 129 + lane + 64];
        float mx = fmaxf(v0, v1);
        for (int off = 32; off; off >>= 1) mx = fmaxf(mx, __shfl_xor(mx, off));
        float e0 = expf(v0 - mx), e1 = expf(v1 - mx);
        float sm = e0 + e1;
        for (int off = 32; off; off >>= 1) sm += __shfl_xor(sm, off);
        float inv = 1.f / sm;
        sa0[rr] = e0 * inv; sa1[rr] = e1 * inv;
    }
    __syncthreads();
#pragma unroll
    for (int rr = 0; rr < 4; ++rr) {
        int q = wid * 4 + rr;
        AsS[q * 136 + lane] = f2s(sa0[rr]);
        AsS[q * 136 + lane + 64] = f2s(sa1[rr]);
    }
    __syncthreads();

    // ---- phase 4: PV MFMA + o_pair (PZ in two 8-chunk batches) ----
    short8 pz0[8];
    if (t < 128) {
        int q = t >> 3, c = t & 7;
        const short8* pzp = (const short8*)(PZb + ((size_t)(rowg + q) * 8 + c) * 128);
#pragma unroll
        for (int k8 = 0; k8 < 8; ++k8) pz0[k8] = pzp[k8];
    }
#pragma unroll
    for (int i = 0; i < 2; ++i) {
        int tt = wid + i * 4;
        if (tt >= 5) break;
        int nt = tt;
        f32x4 acc = {0.f, 0.f, 0.f, 0.f};
#pragma unroll
        for (int kk = 0; kk < 4; ++kk) {
            short8 af  = *(const short8*)(AsS + idx * 136 + kk * 32 + quad * 8);
            short8 bfv = *(const short8*)(VtS + (nt * 16 + idx) * 136 + kk * 32 + quad * 8);
            acc = __builtin_amdgcn_mfma_f32_16x16x32_bf16(af, bfv, acc, 0, 0, 0);
        }
        int x = nt * 16 + idx;
#pragma unroll
        for (int r = 0; r < 4; ++r) {
            int q = quad * 4 + r;
            if (x < 32)
                CATb[(size_t)(rowg + q) * 704 + h * 32 + x] = __float2bfloat16(acc[r]);
            else if (x < 68)
                OPT[q * 37 + (x - 32)] = acc[r];
        }
    }
    if (t < 128) {
        int q = t >> 3, c = t & 7;
        const short8* pzp = (const short8*)(PZb + ((size_t)(rowg + q) * 8 + c) * 128);
        const short8* asp = (const short8*)(AsS + q * 136);
        float acc = 0.f;
#pragma unroll
        for (int k8 = 0; k8 < 8; ++k8) {
            short8 pv = pz0[k8];
            short8 av = asp[k8];
#pragma unroll
            for (int j = 0; j < 8; ++j) acc += us2f(av[j]) * us2f(pv[j]);
        }
#pragma unroll
        for (int k8 = 0; k8 < 8; ++k8) pz0[k8] = pzp[8 + k8];
#pragma unroll
        for (int k8 = 0; k8 < 8; ++k8) {
            short8 pv = pz0[k8];
            short8 av = asp[8 + k8];
#pragma unroll
            for (int j = 0; j < 8; ++j) acc += us2f(av[j]) * us2f(pv[j]);
        }
        CATb[(size_t)(rowg + q) * 704 + 640 + h * 8 + c] = __float2bfloat16(acc);
    }
    __syncthreads();

    // ---- phase 5: inverse rotation + norms ----
    if (t < 192) {
        int q = t / 12, v = t % 12;
        int g = rowg + q;
        const float4* rt = (const float4*)(RT + (size_t)g * 12);
        float4 r0 = rt[0], r1 = rt[1], r2 = rt[2];
        float x = OPT[q * 37 + v * 3 + 0] - r2.y;
        float y = OPT[q * 37 + v * 3 + 1] - r2.z;
        float z = OPT[q * 37 + v * 3 + 2] - r2.w;
        float o0 = r0.x * x + r0.w * y + r1.z * z;   // R^T (x - t)
        float o1 = r0.y * x + r1.x * y + r1.w * z;
        float o2 = r0.z * x + r1.y * y + r2.x * z;
        size_t cb = (size_t)g * 704;
        CATb[cb + 256 + (h * 12 + v) * 3 + 0] = __float2bfloat16(o0);
        CATb[cb + 256 + (h * 12 + v) * 3 + 1] = __float2bfloat16(o1);
        CATb[cb + 256 + (h * 12 + v) * 3 + 2] = __float2bfloat16(o2);
        CATb[cb + 544 + h * 12 + v] = __float2bfloat16(sqrtf(o0 * o0 + o1 * o1 + o2 * o2 + 1e-8f));
    }
}

// ---------------- Kernel 5: final GEMM out = CATb @ FWt^T (K=704 compile-time) ----------------
__global__ __launch_bounds__(256) void k_gemm(
    const bf16* __restrict__ A, const bf16* __restrict__ Bt, void* __restrict__ Cv,
    const void* __restrict__ smask)
{
    int wid = threadIdx.x >> 6, lane = threadIdx.x & 63;
    int tid = blockIdx.x * 4 + wid;
    int mt = tid >> 4, nt = tid & 15;
    int idx = lane & 15, quad = lane >> 4;
    const bf16* Ap = A + (size_t)(mt * 16 + idx) * 704 + quad * 8;
    const bf16* Bp = Bt + (size_t)(nt * 16 + idx) * 704 + quad * 8;
    f32x4 acc = {0.f, 0.f, 0.f, 0.f};
#pragma unroll 4
    for (int k = 0; k < 704; k += 32) {
        short8 af = *(const short8*)(Ap + k);
        short8 bfv = *(const short8*)(Bp + k);
        acc = __builtin_amdgcn_mfma_f32_16x16x32_bf16(af, bfv, acc, 0, 0, 0);
    }
    int orow = mt * 16 + quad * 4;
    int ocol = nt * 16 + idx;
    if (flag_f32(smask)) {
        float* C = (float*)Cv;
#pragma unroll
        for (int r = 0; r < 4; ++r) C[(size_t)(orow + r) * 256 + ocol] = acc[r];
    } else {
        bf16* C = (bf16*)Cv;
#pragma unroll
        for (int r = 0; r < 4; ++r) C[(size_t)(orow + r) * 256 + ocol] = __float2bfloat16(acc[r]);
    }
}

extern "C" void kernel_launch(void* const* d_in, const int* in_sizes, int n_in,
                              void* d_out, int out_size, void* d_ws, size_t ws_size,
                              hipStream_t stream) {
    const void* s       = d_in[0];
    const void* cond    = d_in[1];
    const void* z       = d_in[2];
    const void* trans   = d_in[3];
    const void* rots    = d_in[4];
    const void* s_mask  = d_in[5];
    const void* Wq      = d_in[6];
    const void* Wk      = d_in[7];
    const void* Wv      = d_in[8];
    const void* Wqp     = d_in[9];
    const void* Wkvp    = d_in[10];
    const void* Wb      = d_in[11];
    const void* Wdz     = d_in[12];
    const void* hweights= d_in[13];
    const void* Wout    = d_in[14];
    const void* Wg      = d_in[15];
    const void* bg      = d_in[16];
    const void* Wbeta   = d_in[17];
    const void* bbeta   = d_in[18];
    const void* g_z     = d_in[19];
    const void* b_z     = d_in[20];

    float* ws = (float*)d_ws;
    bf16* POb   = (bf16*)(ws);             // [2048][1440]
    bf16* Bzb   = (bf16*)(ws + 1474560);   // [64][8][32][128]
    bf16* PZb   = (bf16*)(ws + 2523136);   // [2048][8][128]
    bf16* SQb   = (bf16*)(ws + 3571712);   // [2048][256]
    bf16* condb = (bf16*)(ws + 3833856);   // [2048][256]
    bf16* CATb  = (bf16*)(ws + 4358144);   // [2048][704]
    bf16* PWt   = (bf16*)(ws + 5079040);   // [1440][256]
    bf16* GWt   = (bf16*)(ws + 5263360);   // [512][256]
    bf16* FWt   = (bf16*)(ws + 5328896);   // [256][704]
    float* RT   = (float*)(ws + 5419008);  // [2048][12] f32
    float* RS   = (float*)(ws + 5443584);  // [2048][2] f32

    PrepTable tb;
    const float qkscale = 0.10206207261596575f;  // sqrt(1/96), folded into Wq
    tb.src[0] = Wq;   tb.dst[0] = PWt; tb.srcN[0] = 256; tb.nOff[0] = 0;   tb.dstStride[0] = 256; tb.scl[0] = qkscale;
    tb.src[1] = Wk;   tb.dst[1] = PWt; tb.srcN[1] = 256; tb.nOff[1] = 256; tb.dstStride[1] = 256; tb.scl[1] = 1.f;
    tb.src[2] = Wv;   tb.dst[2] = PWt; tb.srcN[2] = 256; tb.nOff[2] = 512; tb.dstStride[2] = 256; tb.scl[2] = 1.f;
    tb.src[3] = Wqp;  tb.dst[3] = PWt; tb.srcN[3] = 192; tb.nOff[3] = 768; tb.dstStride[3] = 256; tb.scl[3] = 1.f;
    tb.src[4] = Wkvp; tb.dst[4] = PWt; tb.srcN[4] = 480; tb.nOff[4] = 960; tb.dstStride[4] = 256; tb.scl[4] = 1.f;
    tb.src[5] = Wg;   tb.dst[5] = GWt; tb.srcN[5] = 256; tb.nOff[5] = 0;   tb.dstStride[5] = 256; tb.scl[5] = 1.f;
    tb.src[6] = Wbeta;tb.dst[6] = GWt; tb.srcN[6] = 256; tb.nOff[6] = 256; tb.dstStride[6] = 256; tb.scl[6] = 1.f;
    tb.src[7] = Wout; tb.dst[7] = FWt; tb.srcN[7] = 256; tb.nOff[7] = 0;   tb.dstStride[7] = 704; tb.scl[7] = 1.f;
    int tc[8] = {64, 64, 64, 48, 120, 64, 64, 176};
    tb.tileOff[0] = 0;
    for (int i = 0; i < 8; ++i) tb.tileOff[i + 1] = tb.tileOff[i] + tc[i];
    tb.s = s; tb.RS = RS;
    tb.cond = cond; tb.condb = condb;

    GzArgs ga;
    ga.SQb = SQb; ga.PWt = PWt; ga.POb = POb;
    ga.z = z; ga.Wb = Wb; ga.Wdz = Wdz; ga.g_z = g_z; ga.b_z = b_z;
    ga.Bzb = Bzb; ga.PZb = PZb;
    ga.rots = rots; ga.trans = trans; ga.RT = RT;

    dim3 blk(256);
    // k_prep: 664 transpose + 256 cond + 256 LN-stats = 1176 blocks
    k_prep<<<dim3(1176), blk, 0, stream>>>(tb, s_mask);
    k_gb<<<dim3(512), blk, 0, stream>>>(condb, GWt, s, RS, bg, bbeta, s_mask, SQb);
    // k_gemm_z: 720 PO-GEMM + 1024 z + 96 RT = 1840 blocks (z/RT overlap the GEMM)
    k_gemm_z<<<dim3(1840), blk, 0, stream>>>(ga, s_mask);
    k_attn_out<<<dim3(1024), blk, 0, stream>>>(POb, Bzb, PZb, RT, s_mask, hweights, CATb);
    k_gemm<<<dim3(512), blk, 0, stream>>>(CATb, FWt, d_out, s_mask);
}